// Round 5
// baseline (155.841 us; speedup 1.0000x reference)
//
#include <hip/hip_runtime.h>

#define B_    16
#define N_    4096
#define S_    1024
#define K_    32
#define DIN_  64
#define DINC_ 67
#define DOUT_ 64
#define ROWS_ (B_ * N_)
#define WP1S  68     // padded w1 row stride (16B-aligned, slot 67 = 0)
#define LSTR  132    // LDS activation row stride in floats (b128 conflict-free)
// combined row layout: 128 ushorts = [proj bf16 x64 | xp bf16 x64] = 256 B

static __device__ __forceinline__ unsigned short f2bf(float f) {
    unsigned int u = __float_as_uint(f);
    u = (u + 0x7fffu + ((u >> 16) & 1u)) >> 16;   // RNE
    return (unsigned short)u;
}
static __device__ __forceinline__ float bf2f(unsigned short h) {
    return __uint_as_float((unsigned int)h << 16);
}

// ---------------------------------------------------------------------------
// Prep: pad w1 rows 67 -> 68 floats (zero slot 67) so weight chunks are
// 16B-aligned scalar dwordx4 streams; copy w2 (already aligned).
// ---------------------------------------------------------------------------
__global__ __launch_bounds__(256) void prep_kernel(
    const float* __restrict__ w1, const float* __restrict__ w2,
    float* __restrict__ wp1, float* __restrict__ wp2)
{
    const int i = blockIdx.x * 256 + threadIdx.x;
    if (i < DOUT_ * WP1S) {
        const int c = i / WP1S, d = i - c * WP1S;
        wp1[i] = (d < DINC_) ? w1[c * DINC_ + d] : 0.f;
    }
    const int j = i - DOUT_ * WP1S;
    if (j >= 0 && j < DOUT_ * DIN_) wp2[j] = w2[j];
}

// ---------------------------------------------------------------------------
// Kernel 1: projection. Block = 256 thr = 4 waves, 64 rows staged in LDS.
// lane = row (per-lane ds_read_b128 activations, stride 132 -> conflict-free);
// wave = 16-channel window (weights via uniform s_load_dwordx4, sK$-resident).
// Accumulators accA/accB[16] are loop-carried -> VGPR-resident by construction.
// Output: bf16 combined rows [proj|xp], halving all downstream traffic.
// ---------------------------------------------------------------------------
__global__ __launch_bounds__(256) void proj_kernel(
    const float* __restrict__ x, const float* __restrict__ xcm,
    const float* __restrict__ wp1, const float* __restrict__ wp2,
    const float* __restrict__ bias, const int* __restrict__ use_x_p,
    unsigned short* __restrict__ cmb)
{
    __shared__ float lact[64 * LSTR];   // [row][0..66]=xc, [67]=0, [68..131]=x
    const int t    = threadIdx.x;
    const int row0 = blockIdx.x * 64;

    {   // coalesced staging
        const float* sc = xcm + (size_t)row0 * DINC_;
        for (int i = t; i < 64 * DINC_; i += 256) {
            const int r = i / DINC_, d = i - r * DINC_;
            lact[r * LSTR + d] = sc[i];
        }
        const float* sx = x + (size_t)row0 * DIN_;
        for (int i = t; i < 64 * DIN_; i += 256) {
            lact[(i >> 6) * LSTR + 68 + (i & 63)] = sx[i];
        }
        if (t < 64) lact[t * LSTR + 67] = 0.f;   // kill the K-tail garbage
    }
    __syncthreads();

    const int r  = t & 63;                                   // my row
    const int w  = __builtin_amdgcn_readfirstlane(t >> 6);   // my wave
    const int cb = w * 16;                                   // channel window
    const int ux = use_x_p[0];

    float accA[16], accB[16];
#pragma unroll
    for (int i = 0; i < 16; ++i) { accA[i] = 0.f; accB[i] = 0.f; }

    const float4* l4 = (const float4*)lact + r * (LSTR / 4);

#pragma unroll
    for (int j = 0; j < 17; ++j) {                 // xc part: d = 0..67 (pad)
        const float4 a = l4[j];
#pragma unroll
        for (int ci = 0; ci < 16; ++ci) {
            const float4 wv = *(const float4*)(wp1 + (size_t)(cb + ci) * WP1S + 4 * j);
            accA[ci] += a.x * wv.x; accA[ci] += a.y * wv.y;
            accA[ci] += a.z * wv.z; accA[ci] += a.w * wv.w;
        }
    }
#pragma unroll
    for (int j = 0; j < 16; ++j) {                 // x part: d = 0..63
        const float4 a = l4[17 + j];
#pragma unroll
        for (int ci = 0; ci < 16; ++ci) {
            const float4 wv = *(const float4*)(wp2 + (size_t)(cb + ci) * DIN_ + 4 * j);
            accB[ci] += a.x * wv.x; accB[ci] += a.y * wv.y;
            accB[ci] += a.z * wv.z; accB[ci] += a.w * wv.w;
        }
    }

    // epilogue: pack bf16 pairs, 4 x 16B stores per lane (L2 merges the row)
    unsigned int pp[8], pq[8];
#pragma unroll
    for (int i = 0; i < 8; ++i) {
        const float p0 = accA[2*i]   + bias[cb + 2*i]   + (ux ? accB[2*i]   : 0.f);
        const float p1 = accA[2*i+1] + bias[cb + 2*i+1] + (ux ? accB[2*i+1] : 0.f);
        pp[i] = (unsigned int)f2bf(p0) | ((unsigned int)f2bf(p1) << 16);
        pq[i] = (unsigned int)f2bf(accB[2*i]) | ((unsigned int)f2bf(accB[2*i+1]) << 16);
    }
    unsigned short* rowp = cmb + (size_t)(row0 + r) * 128;
    *(uint4*)(rowp + cb)          = make_uint4(pp[0], pp[1], pp[2], pp[3]);
    *(uint4*)(rowp + cb + 8)      = make_uint4(pp[4], pp[5], pp[6], pp[7]);
    *(uint4*)(rowp + 64 + cb)     = make_uint4(pq[0], pq[1], pq[2], pq[3]);
    *(uint4*)(rowp + 64 + cb + 8) = make_uint4(pq[4], pq[5], pq[6], pq[7]);
}

// ---------------------------------------------------------------------------
// Kernel 2: gather + masked max + center subtraction on bf16 combined rows.
// One wave per (b,s); lane = channel. Each k-gather = one 128 B line.
// Per-XCD slab = 2 batches x 1 MB -> L2-resident with ~8x reuse.
// ---------------------------------------------------------------------------
__global__ __launch_bounds__(256) void gather_max_kernel(
    const int* __restrict__ indexes, const unsigned short* __restrict__ cmb,
    const int* __restrict__ use_x_p, float* __restrict__ out)
{
    const int lane = threadIdx.x & 63;
    const int wv   = __builtin_amdgcn_readfirstlane(threadIdx.x >> 6);
    const int xcd  = blockIdx.x & 7;
    const int tb   = blockIdx.x >> 3;
    const int pair = xcd * ((B_ * S_) / 8) + tb * 4 + wv;
    const int b    = pair >> 10;   // S_ = 1024
    const int ux   = use_x_p[0];

    const int* idxp = indexes + (size_t)pair * K_;           // uniform -> s_load
    const unsigned short* cbp = cmb + (size_t)b * N_ * 128;

    const float NEG = -__builtin_inff();
    float m = NEG;
#pragma unroll
    for (int k = 0; k < K_; ++k) {
        const int ik  = idxp[k];
        const int iku = ik < 0 ? 0 : ik;
        const float v = bf2f(cbp[(size_t)iku * 128 + lane]); // 128B coalesced
        m = fmaxf(m, ik < 0 ? NEG : v);
    }
    if (ux) {
        const int i0 = idxp[0];                              // always valid
        m -= bf2f(cbp[(size_t)i0 * 128 + 64 + lane]);        // xp half of row
    }
    out[(size_t)pair * 64 + lane] = m;
}

// ---------------------------------------------------------------------------
// Fallback (ws too small): fully fused, recomputes projections per gather.
// ---------------------------------------------------------------------------
__global__ __launch_bounds__(256, 1) void fused_fallback_kernel(
    const float* __restrict__ x, const float* __restrict__ xcm,
    const int* __restrict__ indexes,
    const float* __restrict__ w1, const float* __restrict__ w2,
    const float* __restrict__ bias, const int* __restrict__ use_x_p,
    float* __restrict__ out)
{
    const int lane = threadIdx.x & 63;
    const int pair = (blockIdx.x * blockDim.x + threadIdx.x) >> 6;
    const int b    = pair >> 10;
    const int ux   = use_x_p[0];

    float W1[DINC_];
#pragma unroll
    for (int j = 0; j < DINC_; ++j) W1[j] = w1[lane * DINC_ + j];
    float W2[DIN_];
#pragma unroll
    for (int j = 0; j < DIN_; ++j) W2[j] = w2[lane * DIN_ + j];
    const float bv = bias[lane];

    const int* idxp  = indexes + (size_t)pair * K_;
    const int  myidx = idxp[lane & 31];

    const float NEG = -__builtin_inff();
    float m = NEG;
    for (int k = 0; k < K_; ++k) {
        const int ik = __shfl(myidx, k, 64);
        if (ik < 0) continue;
        const float* xc_row = xcm + ((size_t)b * N_ + ik) * DINC_;
        float a1 = bv;
#pragma unroll
        for (int j = 0; j < DINC_; ++j) a1 += xc_row[j] * W1[j];
        if (ux) {
            const float* x_row = x + ((size_t)b * N_ + ik) * DIN_;
            float a2 = 0.f;
#pragma unroll
            for (int j = 0; j < DIN_; ++j) a2 += x_row[j] * W2[j];
            a1 += a2;
        }
        m = fmaxf(m, a1);
    }
    if (ux) {
        const int i0 = __shfl(myidx, 0, 64);
        const float* x_row = x + ((size_t)b * N_ + i0) * DIN_;
        float a2 = 0.f;
#pragma unroll
        for (int j = 0; j < DIN_; ++j) a2 += x_row[j] * W2[j];
        m -= a2;
    }
    out[(size_t)pair * DOUT_ + lane] = m;
}

extern "C" void kernel_launch(void* const* d_in, const int* in_sizes, int n_in,
                              void* d_out, int out_size, void* d_ws, size_t ws_size,
                              hipStream_t stream)
{
    const float* x    = (const float*)d_in[0];
    const float* xcm  = (const float*)d_in[1];
    const int*   idx  = (const int*)d_in[2];
    const float* w1   = (const float*)d_in[3];
    const float* w2   = (const float*)d_in[4];
    const float* bias = (const float*)d_in[5];
    const int*   ux   = (const int*)d_in[6];
    float* out = (float*)d_out;

    const size_t cmb_bytes = (size_t)ROWS_ * 128 * sizeof(unsigned short); // 16 MiB
    const size_t w_bytes   = (size_t)(DOUT_ * WP1S + DOUT_ * DIN_) * sizeof(float);
    const int npairs = B_ * S_;   // 16384

    if (ws_size >= cmb_bytes + w_bytes) {
        unsigned short* cmb = (unsigned short*)d_ws;
        float* wp1 = (float*)((char*)d_ws + cmb_bytes);
        float* wp2 = wp1 + DOUT_ * WP1S;

        const int prep_n = DOUT_ * WP1S + DOUT_ * DIN_;   // 8448 elements
        prep_kernel<<<(prep_n + 255) / 256, 256, 0, stream>>>(w1, w2, wp1, wp2);
        proj_kernel<<<ROWS_ / 64, 256, 0, stream>>>(x, xcm, wp1, wp2, bias, ux, cmb);
        gather_max_kernel<<<npairs / 4, 256, 0, stream>>>(idx, cmb, ux, out);
    } else {
        fused_fallback_kernel<<<npairs / 4, 256, 0, stream>>>(x, xcm, idx, w1, w2,
                                                              bias, ux, out);
    }
}

// Round 6
// 117.695 us; speedup vs baseline: 1.3241x; 1.3241x over previous
//
#include <hip/hip_runtime.h>

#define B_    16
#define N_    4096
#define S_    1024
#define K_    32
#define DIN_  64
#define DINC_ 67
#define DOUT_ 64
#define ROWS_ (B_ * N_)
#define KPAD  160            // 5 K-steps of 32
#define NCH   128            // 64 proj + 64 xp output columns
#define NFRAG 2560           // 5 ksteps * 8 ntiles * 64 lanes 16B-chunks
// cmb row: 128 bf16 = [proj x64 | xp x64] = 256 B

typedef float f32x4 __attribute__((ext_vector_type(4)));
typedef short s16x8 __attribute__((ext_vector_type(8)));

static __device__ __forceinline__ unsigned short f2bf(float f) {
    unsigned int u = __float_as_uint(f);
    u = (u + 0x7fffu + ((u >> 16) & 1u)) >> 16;   // RNE
    return (unsigned short)u;
}
static __device__ __forceinline__ float bf2f(unsigned short h) {
    return __uint_as_float((unsigned int)h << 16);
}

// ---------------------------------------------------------------------------
// Prep: build MFMA weight fragments (used as the A-operand of the transposed
// GEMM). Chunk id = (kstep*8 + ntile)*64 + lane; element j of the chunk =
// W[k = kstep*32 + (lane>>4)*8 + j][c = ntile*16 + (lane&15)] where
//   c <  64 : proj col  = w1[c][k]        (k<67)  | ux*w2[c][k-67] (67<=k<131)
//   c >= 64 : xp col    = w2[c-64][k-67]  (67<=k<131), else 0
// ux is baked in here (prep runs every launch; use_x is a device scalar).
// ---------------------------------------------------------------------------
__global__ __launch_bounds__(256) void prep_kernel(
    const float* __restrict__ w1, const float* __restrict__ w2,
    const int* __restrict__ use_x_p, uint4* __restrict__ wf)
{
    const int id = blockIdx.x * 256 + threadIdx.x;
    if (id >= NFRAG) return;
    const int s  = id >> 9;
    const int nt = (id >> 6) & 7;
    const int l  = id & 63;
    const int q  = l >> 4, m = l & 15;
    const int c  = nt * 16 + m;
    const int ux = use_x_p[0];

    unsigned int w[4];
#pragma unroll
    for (int p = 0; p < 4; ++p) {
        unsigned short h[2];
#pragma unroll
        for (int e = 0; e < 2; ++e) {
            const int j = p * 2 + e;
            const int k = s * 32 + q * 8 + j;
            float v = 0.f;
            if (c < 64) {
                if (k < DINC_)      v = w1[c * DINC_ + k];
                else if (k < 131)   v = ux ? w2[c * DIN_ + (k - DINC_)] : 0.f;
            } else {
                if (k >= DINC_ && k < 131) v = w2[(c - 64) * DIN_ + (k - DINC_)];
            }
            h[e] = f2bf(v);
        }
        w[p] = (unsigned int)h[0] | ((unsigned int)h[1] << 16);
    }
    wf[id] = make_uint4(w[0], w[1], w[2], w[3]);
}

// ---------------------------------------------------------------------------
// Kernel 1: projection via MFMA 16x16x32 bf16.
// Block = 256 thr = 4 waves = 64 rows; wave w owns rows w*16..w*16+15.
// Transposed GEMM: D[ch][row] = Wfrag (A-op) x Actfrag (B-op) so lane
// fragments hold 4 consecutive channels of one row -> packed dwordx2 stores.
// A activations staged to LDS in frag-chunk-major layout (b128 conflict-floor).
// Block->row swizzle matches gather's XCD batch slabs (blockIdx&7).
// ---------------------------------------------------------------------------
__global__ __launch_bounds__(256) void proj_kernel(
    const float* __restrict__ x, const float* __restrict__ xcm,
    const uint4* __restrict__ wf, const float* __restrict__ bias,
    unsigned short* __restrict__ cmb)
{
    __shared__ uint4 ldsb[NFRAG];        // weight frags, 40 KB
    __shared__ uint4 ldsa[20 * 64];      // activations: [kchunk][row] 16B, 20 KB

    const int t    = threadIdx.x;
    // XCD swizzle: xcd x computes batches 2x,2x+1 (matches gather's reader slab)
    const int row0 = (blockIdx.x & 7) * (ROWS_ / 8) + (blockIdx.x >> 3) * 64;

    // stage weight frags (coalesced, b128-floor LDS writes)
    for (int i = t; i < NFRAG; i += 256) ldsb[i] = wf[i];

    // stage activations: chunk id = kchunk*64 + row; element j -> k = kchunk*8+j
    for (int n = 0; n < 5; ++n) {
        const int id  = n * 256 + t;     // 1280 chunks
        const int row = id & 63;
        const int kc  = id >> 6;         // 0..19
        const float* xc_row = xcm + (size_t)(row0 + row) * DINC_;
        const float* x_row  = x   + (size_t)(row0 + row) * DIN_;
        unsigned int wds[4];
#pragma unroll
        for (int p = 0; p < 4; ++p) {
            unsigned short h[2];
#pragma unroll
            for (int e = 0; e < 2; ++e) {
                const int k = kc * 8 + p * 2 + e;
                float v = 0.f;
                if (k < DINC_)    v = xc_row[k];
                else if (k < 131) v = x_row[k - DINC_];
                h[e] = f2bf(v);
            }
            wds[p] = (unsigned int)h[0] | ((unsigned int)h[1] << 16);
        }
        ldsa[id] = make_uint4(wds[0], wds[1], wds[2], wds[3]);
    }
    __syncthreads();

    const int l = t & 63;
    const int w = __builtin_amdgcn_readfirstlane(t >> 6);
    const int q = l >> 4, m = l & 15;

    const s16x8* bfr = (const s16x8*)ldsb;
    const s16x8* afr = (const s16x8*)ldsa;

    // A-frags for my wave's 16 rows: row-within-block = w*16 + m
    s16x8 af[5];
#pragma unroll
    for (int s = 0; s < 5; ++s)
        af[s] = afr[(s * 4 + q) * 64 + (w * 16 + m)];

    f32x4 acc[8];
#pragma unroll
    for (int nt = 0; nt < 8; ++nt) acc[nt] = (f32x4){0.f, 0.f, 0.f, 0.f};

#pragma unroll
    for (int s = 0; s < 5; ++s) {
#pragma unroll
        for (int nt = 0; nt < 8; ++nt) {
            const s16x8 bf = bfr[(s * 8 + nt) * 64 + l];
            acc[nt] = __builtin_amdgcn_mfma_f32_16x16x32_bf16(bf, af[s], acc[nt], 0, 0, 0);
        }
    }

    // Epilogue: lane holds row (l&15) of wave tile; channels nt*16 + q*4 + reg.
    const int row_g = row0 + w * 16 + m;
    unsigned short* rowp = cmb + (size_t)row_g * NCH;
    const int chq = q * 4;
#pragma unroll
    for (int nt = 0; nt < 8; ++nt) {
        f32x4 a = acc[nt];
        if (nt < 4) {
            const float4 bv = *(const float4*)(bias + nt * 16 + chq);
            a[0] += bv.x; a[1] += bv.y; a[2] += bv.z; a[3] += bv.w;
        }
        const unsigned int lo = (unsigned int)f2bf(a[0]) | ((unsigned int)f2bf(a[1]) << 16);
        const unsigned int hi = (unsigned int)f2bf(a[2]) | ((unsigned int)f2bf(a[3]) << 16);
        *(uint2*)(rowp + nt * 16 + chq) = make_uint2(lo, hi);
    }
}

// ---------------------------------------------------------------------------
// Kernel 2: gather + masked max + center subtraction, 2 pairs per wave.
// lane = (half h, ln): half picks the pair, ln picks a channel PAIR (dword =
// 2 bf16). One dword load per lane per k -> 256 B/instr fully used, 32 VMEM
// per wave. XCD slab: group blockIdx&7 -> batches 2x,2x+1 (same slab proj's
// writer left dirty in this XCD's L2).
// ---------------------------------------------------------------------------
__global__ __launch_bounds__(256) void gather_max_kernel(
    const int* __restrict__ indexes, const unsigned short* __restrict__ cmb,
    const int* __restrict__ use_x_p, float* __restrict__ out)
{
    const int lane = threadIdx.x & 63;
    const int h    = lane >> 5;
    const int ln   = lane & 31;
    const int wv   = __builtin_amdgcn_readfirstlane(threadIdx.x >> 6);
    const int grp  = (blockIdx.x & 7) * 1024 + (blockIdx.x >> 3) * 4 + wv; // 8192 groups
    const int pairA = grp * 2;
    const int b     = grp >> 9;          // 512 groups per batch
    const int ux    = use_x_p[0];

    const int* iA = indexes + (size_t)pairA * K_;       // uniform -> s_load
    const int* iB = iA + K_;
    const char* cb = (const char*)cmb + (size_t)b * N_ * 256;

    const float NEG = -__builtin_inff();
    float m0 = NEG, m1 = NEG;
#pragma unroll
    for (int k = 0; k < K_; ++k) {
        const int ia = iA[k], ib = iB[k];
        const int ik = h ? ib : ia;
        const int iku = ik < 0 ? 0 : ik;
        const unsigned int v = *(const unsigned int*)(cb + ((size_t)iku << 8) + ln * 4);
        const bool inv = ik < 0;
        m0 = fmaxf(m0, inv ? NEG : bf2f((unsigned short)(v & 0xffff)));
        m1 = fmaxf(m1, inv ? NEG : bf2f((unsigned short)(v >> 16)));
    }
    if (ux) {
        const int i0 = h ? iB[0] : iA[0];               // center, always valid
        const unsigned int c = *(const unsigned int*)(cb + ((size_t)i0 << 8) + 128 + ln * 4);
        m0 -= bf2f((unsigned short)(c & 0xffff));
        m1 -= bf2f((unsigned short)(c >> 16));
    }
    const int pair = pairA + h;
    *(float2*)(out + (size_t)pair * 64 + ln * 2) = make_float2(m0, m1);
}

// ---------------------------------------------------------------------------
// Fallback (ws too small): fully fused, recomputes projections per gather.
// ---------------------------------------------------------------------------
__global__ __launch_bounds__(256, 1) void fused_fallback_kernel(
    const float* __restrict__ x, const float* __restrict__ xcm,
    const int* __restrict__ indexes,
    const float* __restrict__ w1, const float* __restrict__ w2,
    const float* __restrict__ bias, const int* __restrict__ use_x_p,
    float* __restrict__ out)
{
    const int lane = threadIdx.x & 63;
    const int pair = (blockIdx.x * blockDim.x + threadIdx.x) >> 6;
    const int b    = pair >> 10;
    const int ux   = use_x_p[0];

    float W1[DINC_];
#pragma unroll
    for (int j = 0; j < DINC_; ++j) W1[j] = w1[lane * DINC_ + j];
    float W2[DIN_];
#pragma unroll
    for (int j = 0; j < DIN_; ++j) W2[j] = w2[lane * DIN_ + j];
    const float bv = bias[lane];

    const int* idxp  = indexes + (size_t)pair * K_;
    const int  myidx = idxp[lane & 31];

    const float NEG = -__builtin_inff();
    float m = NEG;
    for (int k = 0; k < K_; ++k) {
        const int ik = __shfl(myidx, k, 64);
        if (ik < 0) continue;
        const float* xc_row = xcm + ((size_t)b * N_ + ik) * DINC_;
        float a1 = bv;
#pragma unroll
        for (int j = 0; j < DINC_; ++j) a1 += xc_row[j] * W1[j];
        if (ux) {
            const float* x_row = x + ((size_t)b * N_ + ik) * DIN_;
            float a2 = 0.f;
#pragma unroll
            for (int j = 0; j < DIN_; ++j) a2 += x_row[j] * W2[j];
            a1 += a2;
        }
        m = fmaxf(m, a1);
    }
    if (ux) {
        const int i0 = __shfl(myidx, 0, 64);
        const float* x_row = x + ((size_t)b * N_ + i0) * DIN_;
        float a2 = 0.f;
#pragma unroll
        for (int j = 0; j < DIN_; ++j) a2 += x_row[j] * W2[j];
        m -= a2;
    }
    out[(size_t)pair * DOUT_ + lane] = m;
}

extern "C" void kernel_launch(void* const* d_in, const int* in_sizes, int n_in,
                              void* d_out, int out_size, void* d_ws, size_t ws_size,
                              hipStream_t stream)
{
    const float* x    = (const float*)d_in[0];
    const float* xcm  = (const float*)d_in[1];
    const int*   idx  = (const int*)d_in[2];
    const float* w1   = (const float*)d_in[3];
    const float* w2   = (const float*)d_in[4];
    const float* bias = (const float*)d_in[5];
    const int*   ux   = (const int*)d_in[6];
    float* out = (float*)d_out;

    const size_t cmb_bytes = (size_t)ROWS_ * NCH * sizeof(unsigned short); // 16 MiB
    const size_t wf_bytes  = (size_t)NFRAG * 16;                           // 40 KB
    const int npairs = B_ * S_;   // 16384

    if (ws_size >= cmb_bytes + wf_bytes) {
        unsigned short* cmb = (unsigned short*)d_ws;
        uint4* wf = (uint4*)((char*)d_ws + cmb_bytes);

        prep_kernel<<<(NFRAG + 255) / 256, 256, 0, stream>>>(w1, w2, ux, wf);
        proj_kernel<<<ROWS_ / 64, 256, 0, stream>>>(x, xcm, wf, bias, cmb);
        gather_max_kernel<<<(npairs / 2) / 4, 256, 0, stream>>>(idx, cmb, ux, out);
    } else {
        fused_fallback_kernel<<<npairs / 4, 256, 0, stream>>>(x, xcm, idx, w1, w2,
                                                              bias, ux, out);
    }
}

// Round 7
// 109.244 us; speedup vs baseline: 1.4265x; 1.0774x over previous
//
#include <hip/hip_runtime.h>

#define B_    16
#define N_    4096
#define S_    1024
#define K_    32
#define DIN_  64
#define DINC_ 67
#define DOUT_ 64
#define ROWS_ (B_ * N_)
#define NCH   128            // 64 proj + 64 xp output columns
#define NFRAG 2560           // 5 ksteps * 8 ntiles * 64 lanes 16B-chunks
#define ASTR  168            // LDS act row stride in ushorts (336 B = 21*16)
// cmb row: 128 bf16 = [proj x64 | xp x64] = 256 B

typedef float f32x4 __attribute__((ext_vector_type(4)));
typedef short s16x8 __attribute__((ext_vector_type(8)));

static __device__ __forceinline__ unsigned short f2bf(float f) {
    unsigned int u = __float_as_uint(f);
    u = (u + 0x7fffu + ((u >> 16) & 1u)) >> 16;   // RNE
    return (unsigned short)u;
}
static __device__ __forceinline__ float bf2f(unsigned short h) {
    return __uint_as_float((unsigned int)h << 16);
}

// ---------------------------------------------------------------------------
// Prep: build MFMA weight fragments (A-operand of the transposed GEMM).
// Chunk id = (kstep*8 + ntile)*64 + lane; element j = W[k][c],
// k = kstep*32 + (lane>>4)*8 + j, c = ntile*16 + (lane&15):
//   c <  64 : proj col = w1[c][k] (k<67) | ux*w2[c][k-67] (67<=k<131)
//   c >= 64 : xp col   = w2[c-64][k-67]  (67<=k<131), else 0
// ---------------------------------------------------------------------------
__global__ __launch_bounds__(256) void prep_kernel(
    const float* __restrict__ w1, const float* __restrict__ w2,
    const int* __restrict__ use_x_p, uint4* __restrict__ wf)
{
    const int id = blockIdx.x * 256 + threadIdx.x;
    if (id >= NFRAG) return;
    const int s  = id >> 9;
    const int nt = (id >> 6) & 7;
    const int l  = id & 63;
    const int q  = l >> 4, m = l & 15;
    const int c  = nt * 16 + m;
    const int ux = use_x_p[0];

    unsigned int w[4];
#pragma unroll
    for (int p = 0; p < 4; ++p) {
        unsigned short h[2];
#pragma unroll
        for (int e = 0; e < 2; ++e) {
            const int j = p * 2 + e;
            const int k = s * 32 + q * 8 + j;
            float v = 0.f;
            if (c < 64) {
                if (k < DINC_)      v = w1[c * DINC_ + k];
                else if (k < 131)   v = ux ? w2[c * DIN_ + (k - DINC_)] : 0.f;
            } else {
                if (k >= DINC_ && k < 131) v = w2[(c - 64) * DIN_ + (k - DINC_)];
            }
            h[e] = f2bf(v);
        }
        w[p] = (unsigned int)h[0] | ((unsigned int)h[1] << 16);
    }
    wf[id] = make_uint4(w[0], w[1], w[2], w[3]);
}

// ---------------------------------------------------------------------------
// Kernel 1: projection via MFMA 16x16x32 bf16.
// Block = 256 thr = 4 waves = 64 rows. Round-6 fix: activation staging is now
// COALESCED fp32 global loads -> f2bf in-register -> ds_write_b16 into a
// bf16 row-major LDS image (stride 336 B). Each lane then reads its whole
// A-frag as ONE aligned ds_read_b128 (uniform 8-lanes-per-bank-group spread).
// Weight frags staged coalesced to LDS as before. Epilogue unchanged
// (layout verified by r6's passing absmax).
// ---------------------------------------------------------------------------
__global__ __launch_bounds__(256) void proj_kernel(
    const float* __restrict__ x, const float* __restrict__ xcm,
    const uint4* __restrict__ wf, const float* __restrict__ bias,
    unsigned short* __restrict__ cmb)
{
    __shared__ uint4 ldsb[NFRAG];               // weight frags, 40960 B
    __shared__ unsigned short lact[64 * ASTR];  // bf16 act rows, 21504 B

    const int t    = threadIdx.x;
    // XCD swizzle: xcd g computes batches 2g,2g+1 (matches gather's reader slab)
    const int row0 = (blockIdx.x & 7) * (ROWS_ / 8) + (blockIdx.x >> 3) * 64;

    // weight frags: coalesced global -> LDS
    for (int i = t; i < NFRAG; i += 256) ldsb[i] = wf[i];

    // activations: coalesced fp32 reads, bf16 LDS image
    // row layout: [0..66]=xc, [67..130]=x, [131..159]=0 (160..167 unread pad)
    {
        const float* sc = xcm + (size_t)row0 * DINC_;
        for (int i = t; i < 64 * DINC_; i += 256) {
            const int row = i / DINC_, d = i - row * DINC_;
            lact[row * ASTR + d] = f2bf(sc[i]);
        }
        const float* sx = x + (size_t)row0 * DIN_;
        for (int i = t; i < 64 * DIN_; i += 256)
            lact[(i >> 6) * ASTR + DINC_ + (i & 63)] = f2bf(sx[i]);
        for (int i = t; i < 64 * 29; i += 256) {
            const int row = i / 29, d = i - row * 29;
            lact[row * ASTR + 131 + d] = 0;
        }
    }
    __syncthreads();

    const int l = t & 63;
    const int w = __builtin_amdgcn_readfirstlane(t >> 6);
    const int q = l >> 4, m = l & 15;

    // A-frags: one aligned b128 per kstep (byte addr = row*336 + s*64 + q*16)
    const unsigned short* arow = lact + (w * 16 + m) * ASTR;
    s16x8 af[5];
#pragma unroll
    for (int s = 0; s < 5; ++s)
        af[s] = *(const s16x8*)(arow + s * 32 + q * 8);

    const s16x8* bfr = (const s16x8*)ldsb;

    f32x4 acc[8];
#pragma unroll
    for (int nt = 0; nt < 8; ++nt) acc[nt] = (f32x4){0.f, 0.f, 0.f, 0.f};

#pragma unroll
    for (int s = 0; s < 5; ++s) {
#pragma unroll
        for (int nt = 0; nt < 8; ++nt) {
            const s16x8 bf = bfr[(s * 8 + nt) * 64 + l];
            acc[nt] = __builtin_amdgcn_mfma_f32_16x16x32_bf16(bf, af[s], acc[nt], 0, 0, 0);
        }
    }

    // Epilogue: lane holds data-row (l&15); channels nt*16 + q*4 + reg.
    const int row_g = row0 + w * 16 + m;
    unsigned short* rowp = cmb + (size_t)row_g * NCH;
    const int chq = q * 4;
#pragma unroll
    for (int nt = 0; nt < 8; ++nt) {
        f32x4 a = acc[nt];
        if (nt < 4) {
            const float4 bv = *(const float4*)(bias + nt * 16 + chq);
            a[0] += bv.x; a[1] += bv.y; a[2] += bv.z; a[3] += bv.w;
        }
        const unsigned int lo = (unsigned int)f2bf(a[0]) | ((unsigned int)f2bf(a[1]) << 16);
        const unsigned int hi = (unsigned int)f2bf(a[2]) | ((unsigned int)f2bf(a[3]) << 16);
        *(uint2*)(rowp + nt * 16 + chq) = make_uint2(lo, hi);
    }
}

// ---------------------------------------------------------------------------
// Kernel 2: gather + masked max + center subtraction, 2 pairs per wave.
// lane = (half h, ln): one dword = 2 bf16 channels; 256 B/instr fully used.
// XCD slab: blockIdx&7 -> batches 2g,2g+1 (same slab proj left dirty in this
// XCD's L2).
// ---------------------------------------------------------------------------
__global__ __launch_bounds__(256) void gather_max_kernel(
    const int* __restrict__ indexes, const unsigned short* __restrict__ cmb,
    const int* __restrict__ use_x_p, float* __restrict__ out)
{
    const int lane = threadIdx.x & 63;
    const int h    = lane >> 5;
    const int ln   = lane & 31;
    const int wv   = __builtin_amdgcn_readfirstlane(threadIdx.x >> 6);
    const int grp  = (blockIdx.x & 7) * 1024 + (blockIdx.x >> 3) * 4 + wv; // 8192 groups
    const int pairA = grp * 2;
    const int b     = grp >> 9;          // 512 groups per batch
    const int ux    = use_x_p[0];

    const int* iA = indexes + (size_t)pairA * K_;       // uniform -> s_load
    const int* iB = iA + K_;
    const char* cb = (const char*)cmb + (size_t)b * N_ * 256;

    const float NEG = -__builtin_inff();
    float m0 = NEG, m1 = NEG;
#pragma unroll
    for (int k = 0; k < K_; ++k) {
        const int ia = iA[k], ib = iB[k];
        const int ik = h ? ib : ia;
        const int iku = ik < 0 ? 0 : ik;
        const unsigned int v = *(const unsigned int*)(cb + ((size_t)iku << 8) + ln * 4);
        const bool inv = ik < 0;
        m0 = fmaxf(m0, inv ? NEG : bf2f((unsigned short)(v & 0xffff)));
        m1 = fmaxf(m1, inv ? NEG : bf2f((unsigned short)(v >> 16)));
    }
    if (ux) {
        const int i0 = h ? iB[0] : iA[0];               // center, always valid
        const unsigned int c = *(const unsigned int*)(cb + ((size_t)i0 << 8) + 128 + ln * 4);
        m0 -= bf2f((unsigned short)(c & 0xffff));
        m1 -= bf2f((unsigned short)(c >> 16));
    }
    const int pair = pairA + h;
    *(float2*)(out + (size_t)pair * 64 + ln * 2) = make_float2(m0, m1);
}

// ---------------------------------------------------------------------------
// Fallback (ws too small): fully fused, recomputes projections per gather.
// ---------------------------------------------------------------------------
__global__ __launch_bounds__(256, 1) void fused_fallback_kernel(
    const float* __restrict__ x, const float* __restrict__ xcm,
    const int* __restrict__ indexes,
    const float* __restrict__ w1, const float* __restrict__ w2,
    const float* __restrict__ bias, const int* __restrict__ use_x_p,
    float* __restrict__ out)
{
    const int lane = threadIdx.x & 63;
    const int pair = (blockIdx.x * blockDim.x + threadIdx.x) >> 6;
    const int b    = pair >> 10;
    const int ux   = use_x_p[0];

    float W1[DINC_];
#pragma unroll
    for (int j = 0; j < DINC_; ++j) W1[j] = w1[lane * DINC_ + j];
    float W2[DIN_];
#pragma unroll
    for (int j = 0; j < DIN_; ++j) W2[j] = w2[lane * DIN_ + j];
    const float bv = bias[lane];

    const int* idxp  = indexes + (size_t)pair * K_;
    const int  myidx = idxp[lane & 31];

    const float NEG = -__builtin_inff();
    float m = NEG;
    for (int k = 0; k < K_; ++k) {
        const int ik = __shfl(myidx, k, 64);
        if (ik < 0) continue;
        const float* xc_row = xcm + ((size_t)b * N_ + ik) * DINC_;
        float a1 = bv;
#pragma unroll
        for (int j = 0; j < DINC_; ++j) a1 += xc_row[j] * W1[j];
        if (ux) {
            const float* x_row = x + ((size_t)b * N_ + ik) * DIN_;
            float a2 = 0.f;
#pragma unroll
            for (int j = 0; j < DIN_; ++j) a2 += x_row[j] * W2[j];
            a1 += a2;
        }
        m = fmaxf(m, a1);
    }
    if (ux) {
        const int i0 = __shfl(myidx, 0, 64);
        const float* x_row = x + ((size_t)b * N_ + i0) * DIN_;
        float a2 = 0.f;
#pragma unroll
        for (int j = 0; j < DIN_; ++j) a2 += x_row[j] * W2[j];
        m -= a2;
    }
    out[(size_t)pair * DOUT_ + lane] = m;
}

extern "C" void kernel_launch(void* const* d_in, const int* in_sizes, int n_in,
                              void* d_out, int out_size, void* d_ws, size_t ws_size,
                              hipStream_t stream)
{
    const float* x    = (const float*)d_in[0];
    const float* xcm  = (const float*)d_in[1];
    const int*   idx  = (const int*)d_in[2];
    const float* w1   = (const float*)d_in[3];
    const float* w2   = (const float*)d_in[4];
    const float* bias = (const float*)d_in[5];
    const int*   ux   = (const int*)d_in[6];
    float* out = (float*)d_out;

    const size_t cmb_bytes = (size_t)ROWS_ * NCH * sizeof(unsigned short); // 16 MiB
    const size_t wf_bytes  = (size_t)NFRAG * 16;                           // 40 KB
    const int npairs = B_ * S_;   // 16384

    if (ws_size >= cmb_bytes + wf_bytes) {
        unsigned short* cmb = (unsigned short*)d_ws;
        uint4* wf = (uint4*)((char*)d_ws + cmb_bytes);

        prep_kernel<<<(NFRAG + 255) / 256, 256, 0, stream>>>(w1, w2, ux, wf);
        proj_kernel<<<ROWS_ / 64, 256, 0, stream>>>(x, xcm, wf, bias, cmb);
        gather_max_kernel<<<(npairs / 2) / 4, 256, 0, stream>>>(idx, cmb, ux, out);
    } else {
        fused_fallback_kernel<<<npairs / 4, 256, 0, stream>>>(x, xcm, idx, w1, w2,
                                                              bias, ux, out);
    }
}